// Round 2
// baseline (309.168 us; speedup 1.0000x reference)
//
#include <hip/hip_runtime.h>

#define N_NODES 50000
#define N_EDGES 800000
#define SCAN_NB 49   // ceil(50000 / 1024) blocks, 1024 elements per block

typedef __attribute__((ext_vector_type(4))) _Float16 half4;
typedef __attribute__((ext_vector_type(8))) _Float16 half8;

// Recover in-degree from GCN norm: norm = max(deg,1)^-0.5 (fp32).
// deg=0 reconstructs as 1 (harmless over-allocation; aggregate uses the
// post-fill cursor as end pointer, so phantom slots are never read).
__device__ __forceinline__ int deg_from_norm(float n)
{
    return __float2int_rn(1.0f / (n * n));
}

// -------- Kernel A: t = fp16( (h @ W) * norm ) ----------------------------
// K chunked by 32: LDS = 16 KB (W chunk) + 9.2 KB (H tile) -> 4 blocks/CU.
__global__ __launch_bounds__(256, 4) void gemm_scale_kernel(
    const float* __restrict__ h, const float* __restrict__ norm,
    const float* __restrict__ W, _Float16* __restrict__ t)
{
    __shared__ float Ws[32 * 128];    // [k][c] chunk, 16 KB
    __shared__ float Hs[64 * 36];     // [r][k] chunk, padded stride 36, 9 KB
    const int tid = threadIdx.x;
    const int rbase = blockIdx.x * 64;

    const int rt = tid >> 5, ct = tid & 31;
    const int r0 = rt * 8, c0 = ct * 4;
    float acc[8][4];
#pragma unroll
    for (int i = 0; i < 8; ++i)
#pragma unroll
        for (int j = 0; j < 4; ++j) acc[i][j] = 0.f;

    for (int kc = 0; kc < 128; kc += 32) {
        // stage W[kc..kc+31][:] : contiguous 16 KB, 4 float4/thread
        const float4* Wg = (const float4*)(W + (size_t)kc * 128);
        float4* Ws4 = (float4*)Ws;
#pragma unroll
        for (int i = 0; i < 4; ++i)
            Ws4[i * 256 + tid] = Wg[i * 256 + tid];
        // stage H[rbase..rbase+63][kc..kc+31] : 2 float4/thread
#pragma unroll
        for (int i = 0; i < 2; ++i) {
            int f = i * 256 + tid;        // 0..511
            int row = f >> 3;             // 0..63
            int c4 = (f & 7) << 2;        // 0..28
            int gr = rbase + row;
            float4 v = make_float4(0.f, 0.f, 0.f, 0.f);
            if (gr < N_NODES) v = *(const float4*)(h + (size_t)gr * 128 + kc + c4);
            *(float4*)(Hs + row * 36 + c4) = v;
        }
        __syncthreads();

#pragma unroll
        for (int k = 0; k < 32; k += 4) {
            float4 w0 = *(const float4*)(Ws + (k + 0) * 128 + c0);
            float4 w1 = *(const float4*)(Ws + (k + 1) * 128 + c0);
            float4 w2 = *(const float4*)(Ws + (k + 2) * 128 + c0);
            float4 w3 = *(const float4*)(Ws + (k + 3) * 128 + c0);
#pragma unroll
            for (int i = 0; i < 8; ++i) {
                float4 hv = *(const float4*)(Hs + (r0 + i) * 36 + k);
                acc[i][0] += hv.x * w0.x + hv.y * w1.x + hv.z * w2.x + hv.w * w3.x;
                acc[i][1] += hv.x * w0.y + hv.y * w1.y + hv.z * w2.y + hv.w * w3.y;
                acc[i][2] += hv.x * w0.z + hv.y * w1.z + hv.z * w2.z + hv.w * w3.z;
                acc[i][3] += hv.x * w0.w + hv.y * w1.w + hv.z * w2.w + hv.w * w3.w;
            }
        }
        __syncthreads();
    }

#pragma unroll
    for (int i = 0; i < 8; ++i) {
        int gr = rbase + r0 + i;
        if (gr < N_NODES) {
            float nv = norm[gr];
            half4 v;
            v.x = (_Float16)(acc[i][0] * nv);
            v.y = (_Float16)(acc[i][1] * nv);
            v.z = (_Float16)(acc[i][2] * nv);
            v.w = (_Float16)(acc[i][3] * nv);
            *(half4*)(t + (size_t)gr * 128 + c0) = v;
        }
    }
}

// -------- CSR build step 1: per-block degree sums (from norm) -------------
__global__ __launch_bounds__(256) void scan_sums_kernel(
    const float* __restrict__ norm, int* __restrict__ bsum)
{
    const int tid = threadIdx.x;
    const int idx = blockIdx.x * 1024 + tid * 4;
    int s = 0;
    if (idx < N_NODES) {                 // 50000 % 4 == 0: group fully in-range
        float4 n = *(const float4*)(norm + idx);
        s = deg_from_norm(n.x) + deg_from_norm(n.y) +
            deg_from_norm(n.z) + deg_from_norm(n.w);
    }
#pragma unroll
    for (int d = 32; d > 0; d >>= 1) s += __shfl_down(s, d);
    __shared__ int ws[4];
    if ((tid & 63) == 0) ws[tid >> 6] = s;
    __syncthreads();
    if (tid == 0) bsum[blockIdx.x] = ws[0] + ws[1] + ws[2] + ws[3];
}

// -------- CSR build step 2: exclusive scan of 49 block sums (1 wave) ------
__global__ __launch_bounds__(64) void scan_bsum_kernel(
    const int* __restrict__ bsum, int* __restrict__ boff)
{
    const int tid = threadIdx.x;
    int v = (tid < SCAN_NB) ? bsum[tid] : 0;
    int inc = v;
#pragma unroll
    for (int d = 1; d < 64; d <<= 1) {
        int u = __shfl_up(inc, d);
        if (tid >= d) inc += u;
    }
    if (tid < SCAN_NB) boff[tid] = inc - v;   // exclusive prefix
}

// -------- CSR build step 3: block-local scan + write off/cur --------------
__global__ __launch_bounds__(256) void scan_write_kernel(
    const float* __restrict__ norm, const int* __restrict__ boff,
    int* __restrict__ off, int* __restrict__ cur)
{
    const int tid = threadIdx.x;
    const int idx = blockIdx.x * 1024 + tid * 4;

    int4 v = make_int4(0, 0, 0, 0);
    if (idx < N_NODES) {
        float4 n = *(const float4*)(norm + idx);
        v.x = deg_from_norm(n.x); v.y = deg_from_norm(n.y);
        v.z = deg_from_norm(n.z); v.w = deg_from_norm(n.w);
    }
    const int s = v.x + v.y + v.z + v.w;

    const int lane = tid & 63, w = tid >> 6;
    int inc = s;
#pragma unroll
    for (int d = 1; d < 64; d <<= 1) {
        int u = __shfl_up(inc, d);
        if (lane >= d) inc += u;
    }
    __shared__ int wsum[4];
    if (lane == 63) wsum[w] = inc;
    __syncthreads();
    int woff = 0;
    for (int i = 0; i < w; ++i) woff += wsum[i];

    int o0 = boff[blockIdx.x] + woff + inc - s;
    int o1 = o0 + v.x;
    int o2 = o1 + v.y;
    int o3 = o2 + v.z;

    if (idx < N_NODES) {
        int4 ov = make_int4(o0, o1, o2, o3);
        *(int4*)(off + idx) = ov;
        *(int4*)(cur + idx) = ov;
    }
}

// -------- CSR build step 4: fill edge-source lists ------------------------
__global__ __launch_bounds__(256) void fill_kernel(
    const int* __restrict__ src, const int* __restrict__ dst,
    int* __restrict__ cur, int* __restrict__ esrc)
{
    int e = blockIdx.x * blockDim.x + threadIdx.x;
    if (e < N_EDGES) {
        int p = atomicAdd(&cur[dst[e]], 1);
        esrc[p] = src[e];
    }
}

// -------- Kernel D: gather-aggregate (fp16 t) + fused finalize ------------
// 16 lanes per dst node; lane l owns halfs [8l..8l+7] (16 B load per edge).
// End pointer is cur[g] (post-fill), so phantom slots of deg-0 nodes are
// never read.
__global__ __launch_bounds__(256) void aggregate_kernel(
    const int* __restrict__ off, const int* __restrict__ cur,
    const int* __restrict__ esrc, const _Float16* __restrict__ t,
    const float* __restrict__ norm, const float* __restrict__ b,
    float* __restrict__ out)
{
    const int g = blockIdx.x * 16 + (threadIdx.x >> 4);
    if (g >= N_NODES) return;
    const int l = threadIdx.x & 15;
    const int c = l << 3;
    const int i0 = off[g], i1 = cur[g];

    float acc[8];
#pragma unroll
    for (int j = 0; j < 8; ++j) acc[j] = 0.f;

    for (int i = i0; i < i1; ++i) {
        int s = esrc[i];
        half8 v = *(const half8*)(t + (size_t)s * 128 + c);
#pragma unroll
        for (int j = 0; j < 8; ++j) acc[j] += (float)v[j];
    }

    const float nv = norm[g];
    const float4 b0 = *(const float4*)(b + c);
    const float4 b1 = *(const float4*)(b + c + 4);
    float4 o0 = make_float4(acc[0] * nv + b0.x, acc[1] * nv + b0.y,
                            acc[2] * nv + b0.z, acc[3] * nv + b0.w);
    float4 o1 = make_float4(acc[4] * nv + b1.x, acc[5] * nv + b1.y,
                            acc[6] * nv + b1.z, acc[7] * nv + b1.w);
    *(float4*)(out + (size_t)g * 128 + c) = o0;
    *(float4*)(out + (size_t)g * 128 + c + 4) = o1;
}

static inline size_t align256(size_t x) { return (x + 255) & ~(size_t)255; }

extern "C" void kernel_launch(void* const* d_in, const int* in_sizes, int n_in,
                              void* d_out, int out_size, void* d_ws, size_t ws_size,
                              hipStream_t stream)
{
    const float* h    = (const float*)d_in[0];
    const float* norm = (const float*)d_in[1];
    const float* W    = (const float*)d_in[2];
    const float* b    = (const float*)d_in[3];
    const int*   src  = (const int*)d_in[4];
    const int*   dst  = (const int*)d_in[5];
    float* out = (float*)d_out;

    // workspace layout
    char* ws = (char*)d_ws;
    size_t o = 0;
    _Float16* t = (_Float16*)(ws + o);  o = align256(o + (size_t)N_NODES * 128 * 2);
    int* off = (int*)(ws + o);          o = align256(o + (size_t)N_NODES * 4);
    int* cur = (int*)(ws + o);          o = align256(o + (size_t)N_NODES * 4);
    int* esrc = (int*)(ws + o);         o = align256(o + ((size_t)N_EDGES + 1024) * 4);
    int* bsum = (int*)(ws + o);         o = align256(o + (size_t)SCAN_NB * 4);
    int* boff = (int*)(ws + o);         o = align256(o + (size_t)SCAN_NB * 4);

    gemm_scale_kernel<<<(N_NODES + 63) / 64, 256, 0, stream>>>(h, norm, W, t);
    scan_sums_kernel<<<SCAN_NB, 256, 0, stream>>>(norm, bsum);
    scan_bsum_kernel<<<1, 64, 0, stream>>>(bsum, boff);
    scan_write_kernel<<<SCAN_NB, 256, 0, stream>>>(norm, boff, off, cur);
    fill_kernel<<<(N_EDGES + 255) / 256, 256, 0, stream>>>(src, dst, cur, esrc);
    aggregate_kernel<<<(N_NODES + 15) / 16, 256, 0, stream>>>(off, cur, esrc, t, norm, b, out);
}

// Round 3
// 155.715 us; speedup vs baseline: 1.9855x; 1.9855x over previous
//
#include <hip/hip_runtime.h>

#define N_NODES 50000
#define N_EDGES 800000
#define SCAN_NB 49   // ceil(50000 / 1024) blocks, 1024 elements per block

typedef __attribute__((ext_vector_type(4))) _Float16 half4;
typedef __attribute__((ext_vector_type(8))) _Float16 half8;

// Recover in-degree from GCN norm: norm = max(deg,1)^-0.5 (fp32).
// deg=0 reconstructs as 1 (harmless over-allocation; aggregate uses the
// post-fill cursor as end pointer, so phantom slots are never read).
__device__ __forceinline__ int deg_from_norm(float n)
{
    return __float2int_rn(1.0f / (n * n));
}

// -------- Kernel A: t = fp16( (h @ W) * norm ) ----------------------------
// K chunked by 32: LDS = 16 KB (W chunk) + 9.2 KB (H tile) -> ~3 blocks/CU.
// NOTE: no min-waves clause in __launch_bounds__ — forcing 4 blk/CU capped
// VGPRs at 64 and spilled the 8x4 accumulator tile to scratch (round 2:
// FETCH 297 MB, WRITE 564 MB, 255 us). Natural allocation is ~130 VGPR.
__global__ __launch_bounds__(256) void gemm_scale_kernel(
    const float* __restrict__ h, const float* __restrict__ norm,
    const float* __restrict__ W, _Float16* __restrict__ t)
{
    __shared__ float Ws[32 * 128];    // [k][c] chunk, 16 KB
    __shared__ float Hs[64 * 36];     // [r][k] chunk, padded stride 36, 9 KB
    const int tid = threadIdx.x;
    const int rbase = blockIdx.x * 64;

    const int rt = tid >> 5, ct = tid & 31;
    const int r0 = rt * 8, c0 = ct * 4;
    float acc[8][4];
#pragma unroll
    for (int i = 0; i < 8; ++i)
#pragma unroll
        for (int j = 0; j < 4; ++j) acc[i][j] = 0.f;

    for (int kc = 0; kc < 128; kc += 32) {
        // stage W[kc..kc+31][:] : contiguous 16 KB, 4 float4/thread
        const float4* Wg = (const float4*)(W + (size_t)kc * 128);
        float4* Ws4 = (float4*)Ws;
#pragma unroll
        for (int i = 0; i < 4; ++i)
            Ws4[i * 256 + tid] = Wg[i * 256 + tid];
        // stage H[rbase..rbase+63][kc..kc+31] : 2 float4/thread
#pragma unroll
        for (int i = 0; i < 2; ++i) {
            int f = i * 256 + tid;        // 0..511
            int row = f >> 3;             // 0..63
            int c4 = (f & 7) << 2;        // 0..28
            int gr = rbase + row;
            float4 v = make_float4(0.f, 0.f, 0.f, 0.f);
            if (gr < N_NODES) v = *(const float4*)(h + (size_t)gr * 128 + kc + c4);
            *(float4*)(Hs + row * 36 + c4) = v;
        }
        __syncthreads();

#pragma unroll
        for (int k = 0; k < 32; k += 4) {
            float4 w0 = *(const float4*)(Ws + (k + 0) * 128 + c0);
            float4 w1 = *(const float4*)(Ws + (k + 1) * 128 + c0);
            float4 w2 = *(const float4*)(Ws + (k + 2) * 128 + c0);
            float4 w3 = *(const float4*)(Ws + (k + 3) * 128 + c0);
#pragma unroll
            for (int i = 0; i < 8; ++i) {
                float4 hv = *(const float4*)(Hs + (r0 + i) * 36 + k);
                acc[i][0] += hv.x * w0.x + hv.y * w1.x + hv.z * w2.x + hv.w * w3.x;
                acc[i][1] += hv.x * w0.y + hv.y * w1.y + hv.z * w2.y + hv.w * w3.y;
                acc[i][2] += hv.x * w0.z + hv.y * w1.z + hv.z * w2.z + hv.w * w3.z;
                acc[i][3] += hv.x * w0.w + hv.y * w1.w + hv.z * w2.w + hv.w * w3.w;
            }
        }
        __syncthreads();
    }

#pragma unroll
    for (int i = 0; i < 8; ++i) {
        int gr = rbase + r0 + i;
        if (gr < N_NODES) {
            float nv = norm[gr];
            half4 v;
            v.x = (_Float16)(acc[i][0] * nv);
            v.y = (_Float16)(acc[i][1] * nv);
            v.z = (_Float16)(acc[i][2] * nv);
            v.w = (_Float16)(acc[i][3] * nv);
            *(half4*)(t + (size_t)gr * 128 + c0) = v;
        }
    }
}

// -------- CSR build step 1: per-block degree sums (from norm) -------------
__global__ __launch_bounds__(256) void scan_sums_kernel(
    const float* __restrict__ norm, int* __restrict__ bsum)
{
    const int tid = threadIdx.x;
    const int idx = blockIdx.x * 1024 + tid * 4;
    int s = 0;
    if (idx < N_NODES) {                 // 50000 % 4 == 0: group fully in-range
        float4 n = *(const float4*)(norm + idx);
        s = deg_from_norm(n.x) + deg_from_norm(n.y) +
            deg_from_norm(n.z) + deg_from_norm(n.w);
    }
#pragma unroll
    for (int d = 32; d > 0; d >>= 1) s += __shfl_down(s, d);
    __shared__ int ws[4];
    if ((tid & 63) == 0) ws[tid >> 6] = s;
    __syncthreads();
    if (tid == 0) bsum[blockIdx.x] = ws[0] + ws[1] + ws[2] + ws[3];
}

// -------- CSR build step 2: exclusive scan of 49 block sums (1 wave) ------
__global__ __launch_bounds__(64) void scan_bsum_kernel(
    const int* __restrict__ bsum, int* __restrict__ boff)
{
    const int tid = threadIdx.x;
    int v = (tid < SCAN_NB) ? bsum[tid] : 0;
    int inc = v;
#pragma unroll
    for (int d = 1; d < 64; d <<= 1) {
        int u = __shfl_up(inc, d);
        if (tid >= d) inc += u;
    }
    if (tid < SCAN_NB) boff[tid] = inc - v;   // exclusive prefix
}

// -------- CSR build step 3: block-local scan + write off/cur --------------
__global__ __launch_bounds__(256) void scan_write_kernel(
    const float* __restrict__ norm, const int* __restrict__ boff,
    int* __restrict__ off, int* __restrict__ cur)
{
    const int tid = threadIdx.x;
    const int idx = blockIdx.x * 1024 + tid * 4;

    int4 v = make_int4(0, 0, 0, 0);
    if (idx < N_NODES) {
        float4 n = *(const float4*)(norm + idx);
        v.x = deg_from_norm(n.x); v.y = deg_from_norm(n.y);
        v.z = deg_from_norm(n.z); v.w = deg_from_norm(n.w);
    }
    const int s = v.x + v.y + v.z + v.w;

    const int lane = tid & 63, w = tid >> 6;
    int inc = s;
#pragma unroll
    for (int d = 1; d < 64; d <<= 1) {
        int u = __shfl_up(inc, d);
        if (lane >= d) inc += u;
    }
    __shared__ int wsum[4];
    if (lane == 63) wsum[w] = inc;
    __syncthreads();
    int woff = 0;
    for (int i = 0; i < w; ++i) woff += wsum[i];

    int o0 = boff[blockIdx.x] + woff + inc - s;
    int o1 = o0 + v.x;
    int o2 = o1 + v.y;
    int o3 = o2 + v.z;

    if (idx < N_NODES) {
        int4 ov = make_int4(o0, o1, o2, o3);
        *(int4*)(off + idx) = ov;
        *(int4*)(cur + idx) = ov;
    }
}

// -------- CSR build step 4: fill edge-source lists ------------------------
__global__ __launch_bounds__(256) void fill_kernel(
    const int* __restrict__ src, const int* __restrict__ dst,
    int* __restrict__ cur, int* __restrict__ esrc)
{
    int e = blockIdx.x * blockDim.x + threadIdx.x;
    if (e < N_EDGES) {
        int p = atomicAdd(&cur[dst[e]], 1);
        esrc[p] = src[e];
    }
}

// -------- Kernel D: gather-aggregate (fp16 t) + fused finalize ------------
// 16 lanes per dst node; lane l owns halfs [8l..8l+7] (16 B load per edge).
// End pointer is cur[g] (post-fill), so phantom slots of deg-0 nodes are
// never read.
__global__ __launch_bounds__(256) void aggregate_kernel(
    const int* __restrict__ off, const int* __restrict__ cur,
    const int* __restrict__ esrc, const _Float16* __restrict__ t,
    const float* __restrict__ norm, const float* __restrict__ b,
    float* __restrict__ out)
{
    const int g = blockIdx.x * 16 + (threadIdx.x >> 4);
    if (g >= N_NODES) return;
    const int l = threadIdx.x & 15;
    const int c = l << 3;
    const int i0 = off[g], i1 = cur[g];

    float acc[8];
#pragma unroll
    for (int j = 0; j < 8; ++j) acc[j] = 0.f;

    for (int i = i0; i < i1; ++i) {
        int s = esrc[i];
        half8 v = *(const half8*)(t + (size_t)s * 128 + c);
#pragma unroll
        for (int j = 0; j < 8; ++j) acc[j] += (float)v[j];
    }

    const float nv = norm[g];
    const float4 b0 = *(const float4*)(b + c);
    const float4 b1 = *(const float4*)(b + c + 4);
    float4 o0 = make_float4(acc[0] * nv + b0.x, acc[1] * nv + b0.y,
                            acc[2] * nv + b0.z, acc[3] * nv + b0.w);
    float4 o1 = make_float4(acc[4] * nv + b1.x, acc[5] * nv + b1.y,
                            acc[6] * nv + b1.z, acc[7] * nv + b1.w);
    *(float4*)(out + (size_t)g * 128 + c) = o0;
    *(float4*)(out + (size_t)g * 128 + c + 4) = o1;
}

static inline size_t align256(size_t x) { return (x + 255) & ~(size_t)255; }

extern "C" void kernel_launch(void* const* d_in, const int* in_sizes, int n_in,
                              void* d_out, int out_size, void* d_ws, size_t ws_size,
                              hipStream_t stream)
{
    const float* h    = (const float*)d_in[0];
    const float* norm = (const float*)d_in[1];
    const float* W    = (const float*)d_in[2];
    const float* b    = (const float*)d_in[3];
    const int*   src  = (const int*)d_in[4];
    const int*   dst  = (const int*)d_in[5];
    float* out = (float*)d_out;

    // workspace layout
    char* ws = (char*)d_ws;
    size_t o = 0;
    _Float16* t = (_Float16*)(ws + o);  o = align256(o + (size_t)N_NODES * 128 * 2);
    int* off = (int*)(ws + o);          o = align256(o + (size_t)N_NODES * 4);
    int* cur = (int*)(ws + o);          o = align256(o + (size_t)N_NODES * 4);
    int* esrc = (int*)(ws + o);         o = align256(o + ((size_t)N_EDGES + 1024) * 4);
    int* bsum = (int*)(ws + o);         o = align256(o + (size_t)SCAN_NB * 4);
    int* boff = (int*)(ws + o);         o = align256(o + (size_t)SCAN_NB * 4);

    gemm_scale_kernel<<<(N_NODES + 63) / 64, 256, 0, stream>>>(h, norm, W, t);
    scan_sums_kernel<<<SCAN_NB, 256, 0, stream>>>(norm, bsum);
    scan_bsum_kernel<<<1, 64, 0, stream>>>(bsum, boff);
    scan_write_kernel<<<SCAN_NB, 256, 0, stream>>>(norm, boff, off, cur);
    fill_kernel<<<(N_EDGES + 255) / 256, 256, 0, stream>>>(src, dst, cur, esrc);
    aggregate_kernel<<<(N_NODES + 15) / 16, 256, 0, stream>>>(off, cur, esrc, t, norm, b, out);
}